// Round 4
// baseline (296.296 us; speedup 1.0000x reference)
//
#include <hip/hip_runtime.h>
#include <math.h>

// Problem constants (fixed by the reference): N=8, B=4096, D=1024.
#define NN 8
#define BB 4096
#define DD 1024
#define LOG_2PI 1.8378770664093453f

// R6 (resubmit x3 -- R0..R3 benches never ran, GPU at capacity):
// Remove LDS staging entirely. The op is purely elementwise over D with
// ZERO reuse -- LDS staging (R5) cost a 64 KB/block LDS footprint (2 blocks/CU,
// 2 waves/SIMD) and an all-or-nothing vmcnt(0)+barrier drain. Instead each
// thread issues its 16 float4 loads up-front (16 global_load_dwordx4 in
// flight per thread, MLP pinned by sched_barrier so the compiler cannot sink
// loads into the scan), and the compiler's fine-grained vmcnt(N) lets the
// scan begin as soon as plane 0 lands. LDS = 16 B -> occupancy is VGPR-bound
// (~4 waves/SIMD), ~2-4x more latency hiding than R5, with ~256 KB/CU of
// continuously-streaming in-flight loads (vs ~9 KB/CU needed to saturate
// 6.3 TB/s at ~900-cycle HBM latency).

__global__ __launch_bounds__(256) void mpc_kernel(
    const float* __restrict__ means,
    const float* __restrict__ logsig,
    float* __restrict__ out_mean,
    float* __restrict__ out_logvar,
    float* __restrict__ out_logz)
{
    const int b = blockIdx.x;
    const int t = threadIdx.x;
    const int wave = t >> 6;
    const int lane = t & 63;
    const size_t rowoff = (size_t)b * DD + (size_t)t * 4;
    const size_t plane = (size_t)BB * DD;

    // ---- issue ALL 16 loads before any compute (MLP) ----
    float4 M[NN], L[NN];
#pragma unroll
    for (int n = 0; n < NN; ++n) {
        M[n] = *(const float4*)(means  + (size_t)n * plane + rowoff);
        L[n] = *(const float4*)(logsig + (size_t)n * plane + rowoff);
    }
    // Pin load issue above the scan: compiler may not sink loads past here.
    __builtin_amdgcn_sched_barrier(0);

    // ---- scan (4 elements/thread, straight from registers) ----
    float m1[4], v1[4], iv1[4];
    {
        float m[4] = {M[0].x, M[0].y, M[0].z, M[0].w};
        float l[4] = {L[0].x, L[0].y, L[0].z, L[0].w};
#pragma unroll
        for (int j = 0; j < 4; ++j) {
            m1[j]  = m[j];
            v1[j]  = __expf(l[j]);
            iv1[j] = __expf(-l[j]);
        }
    }

    float z = 0.0f;

#pragma unroll
    for (int n = 1; n < NN; ++n) {
        float m2[4] = {M[n].x, M[n].y, M[n].z, M[n].w};
        float l2[4] = {L[n].x, L[n].y, L[n].z, L[n].w};
#pragma unroll
        for (int j = 0; j < 4; ++j) {
            float v2  = __expf(l2[j]);
            float iv2 = __expf(-l2[j]);
            float s   = v1[j] + v2 + 1e-6f;
            float diff = m1[j] - m2[j];
            z += diff * diff * __builtin_amdgcn_rcpf(s) + __logf(s);
            float iv_new = iv1[j] + iv2;
            float cvar   = __builtin_amdgcn_rcpf(iv_new);
            m1[j]  = cvar * (m1[j] * iv1[j] + m2[j] * iv2);
            v1[j]  = cvar;
            iv1[j] = iv_new;
        }
    }

    // ---- elementwise outputs ----
    float4 om = make_float4(m1[0], m1[1], m1[2], m1[3]);
    float4 ol = make_float4(__logf(v1[0]), __logf(v1[1]),
                            __logf(v1[2]), __logf(v1[3]));
    *(float4*)(out_mean + rowoff)   = om;
    *(float4*)(out_logvar + rowoff) = ol;

    // ---- row reduction of z (256 threads = 4 waves of 64) ----
#pragma unroll
    for (int o = 32; o > 0; o >>= 1)
        z += __shfl_down(z, o, 64);

    __shared__ float sz[4];
    if (lane == 0) sz[wave] = z;
    __syncthreads();
    if (t == 0) {
        float total = sz[0] + sz[1] + sz[2] + sz[3];
        out_logz[b] = -0.5f * (total + (float)((NN - 1) * DD) * LOG_2PI);
    }
}

extern "C" void kernel_launch(void* const* d_in, const int* in_sizes, int n_in,
                              void* d_out, int out_size, void* d_ws, size_t ws_size,
                              hipStream_t stream) {
    const float* means  = (const float*)d_in[0];
    const float* logsig = (const float*)d_in[1];
    float* out = (float*)d_out;
    float* out_mean   = out;
    float* out_logvar = out + (size_t)BB * DD;
    float* out_logz   = out + 2 * (size_t)BB * DD;
    mpc_kernel<<<BB, 256, 0, stream>>>(means, logsig, out_mean, out_logvar, out_logz);
}

// Round 7
// 291.848 us; speedup vs baseline: 1.0152x; 1.0152x over previous
//
#include <hip/hip_runtime.h>
#include <math.h>

// Problem constants (fixed by the reference): N=8, B=4096, D=1024.
#define NN 8
#define BB 4096
#define DD 1024
#define LOG_2PI 1.8378770664093453f

// R7b: R7 with the nontemporal-store compile error fixed (builtin requires a
// native vector pointee, not HIP_vector_type float4 -> use ext_vector_type).
//
// R7 rationale (from R6 post-mortem): VGPR=52 proved the compiler rewrote
// "issue all 16 loads up-front" into a ~2-4-deep interleave (64 VGPRs of load
// results can't fit in 52) -> ~2-4 KB MLP/wave -> 1.3 TB/s, latency-bound.
// R7 structure: ONE WAVE PER ROW (64 lanes x 16 elems = 1024 = D), register
// double-buffer at plane-pair granularity. Computing pair n requires its 32
// VGPRs live while pair n+1's 8 float4 loads (8 KB/wave) are in flight --
// the registers are architecturally required, so the pipeline survives.
// Zero LDS, zero barriers (z-reduce is wave-local shuffle). Steady state:
// vmcnt never drains; ~96 KB/CU sustained in flight.

typedef float f32x4 __attribute__((ext_vector_type(4)));

__global__ __launch_bounds__(256) void mpc_kernel(
    const float* __restrict__ means,
    const float* __restrict__ logsig,
    float* __restrict__ out_mean,
    float* __restrict__ out_logvar,
    float* __restrict__ out_logz)
{
    const int t    = threadIdx.x;
    const int wave = t >> 6;
    const int lane = t & 63;
    const int row  = (blockIdx.x << 2) + wave;      // 1024 blocks x 4 waves
    const size_t plane   = (size_t)BB * DD;
    const size_t rowbase = (size_t)row * DD;
    const int off = lane * 4;                        // chunk k covers 1 KB coalesced

    // ---- double-buffered plane-pair pipeline ----
    f32x4 bm[2][4], bl[2][4];

#pragma unroll
    for (int k = 0; k < 4; ++k) {
        bm[0][k] = *(const f32x4*)(means  + rowbase + k * 256 + off);
        bl[0][k] = *(const f32x4*)(logsig + rowbase + k * 256 + off);
    }

    float m1[16], v1[16], iv1[16];
    float z = 0.0f;

#pragma unroll
    for (int n = 0; n < NN; ++n) {
        // issue next pair's 8 loads BEFORE computing current pair
        if (n + 1 < NN) {
            const size_t pb = (size_t)(n + 1) * plane + rowbase;
#pragma unroll
            for (int k = 0; k < 4; ++k) {
                bm[(n + 1) & 1][k] = *(const f32x4*)(means  + pb + k * 256 + off);
                bl[(n + 1) & 1][k] = *(const f32x4*)(logsig + pb + k * 256 + off);
            }
        }
        // pin: prefetch issue stays above the compute of the current pair
        __builtin_amdgcn_sched_barrier(0);

#pragma unroll
        for (int k = 0; k < 4; ++k) {
            const float mk[4] = {bm[n & 1][k].x, bm[n & 1][k].y,
                                 bm[n & 1][k].z, bm[n & 1][k].w};
            const float lk[4] = {bl[n & 1][k].x, bl[n & 1][k].y,
                                 bl[n & 1][k].z, bl[n & 1][k].w};
#pragma unroll
            for (int j = 0; j < 4; ++j) {
                const int e = k * 4 + j;
                if (n == 0) {
                    m1[e]  = mk[j];
                    v1[e]  = __expf(lk[j]);
                    iv1[e] = __expf(-lk[j]);
                } else {
                    float v2   = __expf(lk[j]);
                    float iv2  = __expf(-lk[j]);
                    float s    = v1[e] + v2 + 1e-6f;
                    float d    = m1[e] - mk[j];
                    z += d * d * __builtin_amdgcn_rcpf(s) + __logf(s);
                    float ivn  = iv1[e] + iv2;
                    float cv   = __builtin_amdgcn_rcpf(ivn);
                    m1[e]  = cv * (m1[e] * iv1[e] + mk[j] * iv2);
                    v1[e]  = cv;
                    iv1[e] = ivn;
                }
            }
        }
    }

    // ---- outputs (nontemporal: don't evict LLC-resident inputs) ----
#pragma unroll
    for (int k = 0; k < 4; ++k) {
        f32x4 om = {m1[k*4+0], m1[k*4+1], m1[k*4+2], m1[k*4+3]};
        f32x4 ol = {__logf(v1[k*4+0]), __logf(v1[k*4+1]),
                    __logf(v1[k*4+2]), __logf(v1[k*4+3])};
        __builtin_nontemporal_store(om, (f32x4*)(out_mean   + rowbase + k * 256 + off));
        __builtin_nontemporal_store(ol, (f32x4*)(out_logvar + rowbase + k * 256 + off));
    }

    // ---- wave-local z reduction (no LDS, no barrier) ----
#pragma unroll
    for (int o = 32; o > 0; o >>= 1)
        z += __shfl_down(z, o, 64);
    if (lane == 0)
        out_logz[row] = -0.5f * (z + (float)((NN - 1) * DD) * LOG_2PI);
}

extern "C" void kernel_launch(void* const* d_in, const int* in_sizes, int n_in,
                              void* d_out, int out_size, void* d_ws, size_t ws_size,
                              hipStream_t stream) {
    const float* means  = (const float*)d_in[0];
    const float* logsig = (const float*)d_in[1];
    float* out = (float*)d_out;
    float* out_mean   = out;
    float* out_logvar = out + (size_t)BB * DD;
    float* out_logz   = out + 2 * (size_t)BB * DD;
    mpc_kernel<<<BB / 4, 256, 0, stream>>>(means, logsig, out_mean, out_logvar, out_logz);
}